// Round 1
// 508.519 us; speedup vs baseline: 1.1145x; 1.1145x over previous
//
#include <hip/hip_runtime.h>

typedef __bf16 bf16;
typedef bf16 bf16x8 __attribute__((ext_vector_type(8)));
typedef bf16 bf16x4 __attribute__((ext_vector_type(4)));
typedef float floatx4 __attribute__((ext_vector_type(4)));

__device__ __forceinline__ float mish_f(float x) {
  // mish(x) = x * tanh(softplus(x)) = x * (p^2-1)/(p^2+1), p = 1+e^x
  float e = __expf(fminf(x, 20.0f));
  float p = 1.0f + e;
  float p2 = p * p;
  return x * (p2 - 1.0f) * __builtin_amdgcn_rcpf(p2 + 1.0f);
}

// ------------------------------------------------------------------
// Prep: fp32 -> bf16 for embeddings (row-major) and the 8 weight
// matrices (MFMA B-fragment order).
// B-frag layout for mfma_f32_16x16x32_bf16:
//   Wp[((kt*(D/16)+ct)*64 + lane)*8 + j] = W[kt*32 + (lane>>4)*8 + j][ct*16 + (lane&15)]
// Note: kt-major layout means rows k in [0,128) of a 256x256 matrix are
// exactly the first half of the fragment buffer (kt<4) -> W1_top/W1_bot
// halves are contiguous sub-buffers. uv_kernel relies on this.
// ------------------------------------------------------------------
struct PrepArgs {
  const float* emb;
  const float* W[8];   // W1_p0, W2_p0, W1_p1, W2_p1, W1_p2, W2_p2, W1_p3, W2_p3
  bf16* emb_bf;
  bf16* Wp[8];
};

__global__ __launch_bounds__(256) void prep_kernel(PrepArgs a) {
  const int idx = blockIdx.x * 256 + threadIdx.x;
  const int EMB_N = 2048 * 128;
  if (idx < EMB_N) {
    a.emb_bf[idx] = (bf16)a.emb[idx];
    return;
  }
  int t = idx - EMB_N;
  int m, local, D, lognct;
  if (t < 32768) {            // p0: two 128x128 matrices
    m = t >> 14; local = t & 16383; D = 128; lognct = 3;
  } else {                    // p1..p3: six 256x256 matrices
    int u = t - 32768;
    m = 2 + (u >> 16); local = u & 65535; D = 256; lognct = 4;
  }
  if (m >= 8) return;
  const int j    = local & 7;
  const int lane = (local >> 3) & 63;
  const int ctk  = local >> 9;
  const int ct   = ctk & ((1 << lognct) - 1);
  const int kt   = ctk >> lognct;
  const int row  = kt * 32 + (lane >> 4) * 8 + j;
  const int col  = ct * 16 + (lane & 15);
  a.Wp[m][local] = (bf16)a.W[m][row * D + col];
}

// ------------------------------------------------------------------
// Shared GEMM inner loop: 64 rows (4 m-tiles) x (CPW*16) cols per wave,
// K = NKT*32, A from LDS (row stride STRIDE bf16), B from fragment-order
// global memory.
// ------------------------------------------------------------------
template <int NCT, int NKT, int STRIDE, int CPW>
__device__ __forceinline__ void gemm_tiles(const bf16* lds_a,
                                           const bf16* __restrict__ Wp,
                                           int w, int lane,
                                           floatx4 acc[4][CPW]) {
  const int l15 = lane & 15;
  const int q   = lane >> 4;
  for (int kt = 0; kt < NKT; ++kt) {
    bf16x8 af[4];
#pragma unroll
    for (int mt = 0; mt < 4; ++mt)
      af[mt] = *(const bf16x8*)&lds_a[(mt * 16 + l15) * STRIDE + kt * 32 + q * 8];
    bf16x8 bfr[CPW];
#pragma unroll
    for (int c = 0; c < CPW; ++c)
      bfr[c] = *(const bf16x8*)(Wp + (((kt * NCT) + (w * CPW + c)) * 64 + lane) * 8);
#pragma unroll
    for (int mt = 0; mt < 4; ++mt)
#pragma unroll
      for (int c = 0; c < CPW; ++c)
        acc[mt][c] = __builtin_amdgcn_mfma_f32_16x16x32_bf16(af[mt], bfr[c], acc[mt][c], 0, 0, 0);
  }
}

// ------------------------------------------------------------------
// UV kernel: U = X @ W1_top + b1, V = X @ W1_bot  (per predicate p1..p3)
// X: [2048,128] bf16 rows; W1_top = frag kt 0..3, W1_bot = frag kt 4..7.
// One WG = 64 rows x 256 cols, both U and V (A rows staged once).
// ------------------------------------------------------------------
struct UVArgs {
  const bf16* emb_bf;
  const bf16* W1p[3];
  const float* b1[3];
  float* U[3];
  float* V[3];
};

__global__ __launch_bounds__(256) void uv_kernel(UVArgs a) {
  const int p  = blockIdx.y;
  const int r0 = blockIdx.x * 64;
  const int t  = threadIdx.x;
  const int lane = t & 63;
  const int w    = t >> 6;
  const int l15  = lane & 15;
  const int q    = lane >> 4;

  __shared__ bf16 lds[64 * 136];

  {
    const int row = t >> 2;
    const int qt  = t & 3;
    const uint4* s4 = (const uint4*)(a.emb_bf + (r0 + row) * 128 + qt * 32);
    uint4* d4 = (uint4*)&lds[row * 136 + qt * 32];
#pragma unroll
    for (int u = 0; u < 4; ++u) d4[u] = s4[u];
  }
  __syncthreads();

  floatx4 acc[4][4];

  // ---- U pass (k rows 0..127 of W1 -> frag kt 0..3)
#pragma unroll
  for (int mt = 0; mt < 4; ++mt)
#pragma unroll
    for (int c = 0; c < 4; ++c) acc[mt][c] = (floatx4){0.f, 0.f, 0.f, 0.f};
  gemm_tiles<16, 4, 136, 4>(lds, a.W1p[p], w, lane, acc);

  float b1v[4];
#pragma unroll
  for (int c = 0; c < 4; ++c) b1v[c] = a.b1[p][w * 64 + c * 16 + l15];

  float* Up = a.U[p] + (size_t)r0 * 256;
#pragma unroll
  for (int mt = 0; mt < 4; ++mt)
#pragma unroll
    for (int c = 0; c < 4; ++c) {
      const int col = w * 64 + c * 16 + l15;
#pragma unroll
      for (int r = 0; r < 4; ++r) {
        const int rl = mt * 16 + q * 4 + r;
        Up[rl * 256 + col] = acc[mt][c][r] + b1v[c];
      }
    }

  // ---- V pass (k rows 128..255 -> frag kt 4..7 = +32768 elements)
#pragma unroll
  for (int mt = 0; mt < 4; ++mt)
#pragma unroll
    for (int c = 0; c < 4; ++c) acc[mt][c] = (floatx4){0.f, 0.f, 0.f, 0.f};
  gemm_tiles<16, 4, 136, 4>(lds, a.W1p[p] + 32768, w, lane, acc);

  float* Vp = a.V[p] + (size_t)r0 * 256;
#pragma unroll
  for (int mt = 0; mt < 4; ++mt)
#pragma unroll
    for (int c = 0; c < 4; ++c) {
      const int col = w * 64 + c * 16 + l15;
#pragma unroll
      for (int r = 0; r < 4; ++r) {
        const int rl = mt * 16 + q * 4 + r;
        Vp[rl * 256 + col] = acc[mt][c][r];
      }
    }
}

// ------------------------------------------------------------------
// Arity-2 fused kernel: h = mish(U_i + V_j) -> LDS (bf16), then
// out = h @ W2 + b2 + residual. One WG = 64 pair rows (fixed b,i;
// j = 0..63) x 256 cols. blockIdx.y = predicate.
// ------------------------------------------------------------------
struct A2Args {
  const float* U[3];
  const float* V[3];
  const float* emb_f;
  const bf16* W2p[3];
  const float* b2[3];
  float* out[3];
};

__global__ __launch_bounds__(256, 4) void fused_a2(A2Args a) {
  const int p  = blockIdx.y;
  const int r0 = blockIdx.x * 64;
  const int bb = r0 >> 12;          // batch index
  const int ii = (r0 >> 6) & 63;    // left object index (fixed per WG)
  const int t  = threadIdx.x;
  const int lane = t & 63;
  const int w    = t >> 6;
  const int l15  = lane & 15;
  const int q    = lane >> 4;

  __shared__ bf16 lds[64 * 264];    // H rows for GEMM2

  // ---- Phase 1: h[j][col] = mish(U_i[col] + V_j[col]), bf16x4 LDS writes
  {
    const int col4 = t & 63;        // float4 column chunk: cols col4*4 .. +3
    const int wq   = t >> 6;        // rows wq*16 .. +15
    const floatx4 uvv =
        ((const floatx4*)(a.U[p] + (size_t)(bb * 64 + ii) * 256))[col4];
    const float* Vblk = a.V[p] + (size_t)(bb * 64) * 256;
#pragma unroll
    for (int r = 0; r < 16; ++r) {
      const int row = wq * 16 + r;
      const floatx4 v = ((const floatx4*)(Vblk + row * 256))[col4];
      bf16x4 hv;
#pragma unroll
      for (int e = 0; e < 4; ++e) hv[e] = (bf16)mish_f(uvv[e] + v[e]);
      *(bf16x4*)&lds[row * 264 + col4 * 4] = hv;
    }
  }
  __syncthreads();

  // ---- GEMM2: H @ W2
  floatx4 acc[4][4];
#pragma unroll
  for (int mt = 0; mt < 4; ++mt)
#pragma unroll
    for (int c = 0; c < 4; ++c) acc[mt][c] = (floatx4){0.f, 0.f, 0.f, 0.f};
  gemm_tiles<16, 8, 264, 4>(lds, a.W2p[p], w, lane, acc);

  // ---- Epilogue: + b2 + fp32 residual, nontemporal store
  float b2v[4];
  {
    const float* b2 = a.b2[p];
#pragma unroll
    for (int c = 0; c < 4; ++c) b2v[c] = b2[w * 64 + c * 16 + l15];
  }
  const float* embL = a.emb_f + (size_t)(bb * 64 + ii) * 128;
  const float* embR = a.emb_f + (size_t)(bb * 64) * 128;
  float* outp = a.out[p] + (size_t)r0 * 256;

  if (w < 2) {  // cols 0..127: left residual, same for every row in tile
    float resv[4];
#pragma unroll
    for (int c = 0; c < 4; ++c) resv[c] = embL[w * 64 + c * 16 + l15];
#pragma unroll
    for (int mt = 0; mt < 4; ++mt)
#pragma unroll
      for (int c = 0; c < 4; ++c) {
        const int col = w * 64 + c * 16 + l15;
#pragma unroll
        for (int r = 0; r < 4; ++r) {
          const int rl = mt * 16 + q * 4 + r;
          __builtin_nontemporal_store(acc[mt][c][r] + b2v[c] + resv[c],
                                      &outp[rl * 256 + col]);
        }
      }
  } else {      // cols 128..255: right residual depends on row (j = rl)
#pragma unroll
    for (int mt = 0; mt < 4; ++mt)
#pragma unroll
      for (int c = 0; c < 4; ++c) {
        const int col = w * 64 + c * 16 + l15;
#pragma unroll
        for (int r = 0; r < 4; ++r) {
          const int rl = mt * 16 + q * 4 + r;
          __builtin_nontemporal_store(
              acc[mt][c][r] + b2v[c] + embR[rl * 128 + (col - 128)],
              &outp[rl * 256 + col]);
        }
      }
  }
}

// ------------------------------------------------------------------
// Arity-1 fused residual MLP (D = 128), p0. 32 WGs of 64 rows.
// ------------------------------------------------------------------
struct A1Args {
  const bf16* emb_bf;
  const float* emb_f;
  const bf16* W1p;
  const float* b1;
  const bf16* W2p;
  const float* b2;
  float* out;
};

__global__ __launch_bounds__(256, 4) void fused_a1(A1Args a) {
  const int r0 = blockIdx.x * 64;
  const int t  = threadIdx.x;
  const int lane = t & 63;
  const int w    = t >> 6;
  const int l15  = lane & 15;
  const int q    = lane >> 4;

  __shared__ bf16 lds[64 * 136];

  {
    const int row = t >> 2;
    const int qt  = t & 3;
    const bf16* src = a.emb_bf + (r0 + row) * 128 + qt * 32;
    const uint4* s4 = (const uint4*)src;
    uint4* d4 = (uint4*)&lds[row * 136 + qt * 32];
#pragma unroll
    for (int u = 0; u < 4; ++u) d4[u] = s4[u];
  }
  __syncthreads();

  floatx4 acc[4][2];
#pragma unroll
  for (int mt = 0; mt < 4; ++mt)
#pragma unroll
    for (int c = 0; c < 2; ++c) acc[mt][c] = (floatx4){0.f, 0.f, 0.f, 0.f};
  gemm_tiles<8, 4, 136, 2>(lds, a.W1p, w, lane, acc);

  float b1v[2];
#pragma unroll
  for (int c = 0; c < 2; ++c) b1v[c] = a.b1[w * 32 + c * 16 + l15];

  __syncthreads();
#pragma unroll
  for (int mt = 0; mt < 4; ++mt)
#pragma unroll
    for (int c = 0; c < 2; ++c) {
      const int col = w * 32 + c * 16 + l15;
#pragma unroll
      for (int r = 0; r < 4; ++r) {
        float x = acc[mt][c][r] + b1v[c];
        lds[(mt * 16 + q * 4 + r) * 136 + col] = (bf16)mish_f(x);
      }
    }
  __syncthreads();

#pragma unroll
  for (int mt = 0; mt < 4; ++mt)
#pragma unroll
    for (int c = 0; c < 2; ++c) acc[mt][c] = (floatx4){0.f, 0.f, 0.f, 0.f};
  gemm_tiles<8, 4, 136, 2>(lds, a.W2p, w, lane, acc);

  float b2v[2];
#pragma unroll
  for (int c = 0; c < 2; ++c) b2v[c] = a.b2[w * 32 + c * 16 + l15];

#pragma unroll
  for (int mt = 0; mt < 4; ++mt)
#pragma unroll
    for (int c = 0; c < 2; ++c) {
      const int col = w * 32 + c * 16 + l15;
#pragma unroll
      for (int r = 0; r < 4; ++r) {
        const int rl = mt * 16 + q * 4 + r;
        a.out[(r0 + rl) * 128 + col] =
            acc[mt][c][r] + b2v[c] + a.emb_f[(r0 + rl) * 128 + col];
      }
    }
}

// ------------------------------------------------------------------
extern "C" void kernel_launch(void* const* d_in, const int* in_sizes, int n_in,
                              void* d_out, int out_size, void* d_ws, size_t ws_size,
                              hipStream_t stream) {
  const float* emb_f = (const float*)d_in[0];
  // d_in: 0 emb, 1 num_objects, then W1,b1,W2,b2 per predicate p0..p3
  const float* W1s[4], *b1s[4], *W2s[4], *b2s[4];
  for (int p = 0; p < 4; ++p) {
    W1s[p] = (const float*)d_in[2 + p * 4 + 0];
    b1s[p] = (const float*)d_in[2 + p * 4 + 1];
    W2s[p] = (const float*)d_in[2 + p * 4 + 2];
    b2s[p] = (const float*)d_in[2 + p * 4 + 3];
  }

  char* ws = (char*)d_ws;
  bf16* emb_bf = (bf16*)ws;
  size_t off = (size_t)2048 * 128 * 2;  // 524288
  bf16* Wp[8];
  const size_t wbytes[8] = {32768, 32768, 131072, 131072, 131072, 131072, 131072, 131072};
  for (int m = 0; m < 8; ++m) { Wp[m] = (bf16*)(ws + off); off += wbytes[m]; }
  // U/V buffers: 3 preds x (U,V) x [2048][256] fp32 = 12.6 MB, after weights
  float* Ub[3];
  float* Vb[3];
  for (int p = 0; p < 3; ++p) {
    Ub[p] = (float*)(ws + off) + (size_t)p * 2 * 2048 * 256;
    Vb[p] = Ub[p] + (size_t)2048 * 256;
  }

  PrepArgs pa;
  pa.emb = emb_f;
  pa.emb_bf = emb_bf;
  const float* Wsrc[8] = {W1s[0], W2s[0], W1s[1], W2s[1], W1s[2], W2s[2], W1s[3], W2s[3]};
  for (int m = 0; m < 8; ++m) { pa.W[m] = Wsrc[m]; pa.Wp[m] = Wp[m]; }
  // total elements: 262144 (emb) + 425984 (weights) = 688128 = 2688 * 256
  prep_kernel<<<2688, 256, 0, stream>>>(pa);

  UVArgs uva;
  uva.emb_bf = emb_bf;
  for (int p = 0; p < 3; ++p) {
    uva.W1p[p] = Wp[2 + p * 2];
    uva.b1[p]  = b1s[p + 1];
    uva.U[p]   = Ub[p];
    uva.V[p]   = Vb[p];
  }
  uv_kernel<<<dim3(32, 3), 256, 0, stream>>>(uva);

  float* out = (float*)d_out;

  A1Args a1;
  a1.emb_bf = emb_bf; a1.emb_f = emb_f;
  a1.W1p = Wp[0]; a1.b1 = b1s[0]; a1.W2p = Wp[1]; a1.b2 = b2s[0];
  a1.out = out;
  fused_a1<<<32, 256, 0, stream>>>(a1);

  A2Args a2;
  a2.emb_f = emb_f;
  size_t o = 2048 * 128;  // after p0 output
  for (int p = 0; p < 3; ++p) {
    a2.U[p] = Ub[p];
    a2.V[p] = Vb[p];
    a2.W2p[p] = Wp[3 + p * 2];
    a2.b2[p] = b2s[p + 1];
    a2.out[p] = out + o + (size_t)p * 131072 * 256;
  }
  fused_a2<<<dim3(2048, 3), 256, 0, stream>>>(a2);
}